// Round 3
// baseline (1107.353 us; speedup 1.0000x reference)
//
#include <hip/hip_runtime.h>

#define N_USERS_C 100000
#define N_ITEMS_C 40000
#define NTOT_C    140000
#define DIM_C     64
#define SCAN_B    256

// ---------------------------------------------------------------------------
// CSR build: histogram -> chunked inclusive scan -> partials scan -> finalize
// ---------------------------------------------------------------------------
__global__ __launch_bounds__(256) void hist_rows(
    const int* __restrict__ rows, int* __restrict__ counts, int nnz) {
    int e = blockIdx.x * blockDim.x + threadIdx.x;
    if (e < nnz) atomicAdd(&counts[rows[e]], 1);
}

__global__ __launch_bounds__(SCAN_B) void scan_chunks(
    const int* __restrict__ counts, int* __restrict__ tmp,
    int* __restrict__ partials, int n) {
    __shared__ int s[SCAN_B];
    int i = blockIdx.x * SCAN_B + threadIdx.x;
    int v = (i < n) ? counts[i] : 0;
    s[threadIdx.x] = v;
    __syncthreads();
    #pragma unroll
    for (int off = 1; off < SCAN_B; off <<= 1) {
        int t = (threadIdx.x >= off) ? s[threadIdx.x - off] : 0;
        __syncthreads();
        s[threadIdx.x] += t;
        __syncthreads();
    }
    if (i < n) tmp[i] = s[threadIdx.x];
    if (threadIdx.x == SCAN_B - 1) partials[blockIdx.x] = s[SCAN_B - 1];
}

__global__ __launch_bounds__(SCAN_B) void scan_partials(int* __restrict__ partials, int C) {
    __shared__ int s[SCAN_B];
    __shared__ int carry;
    if (threadIdx.x == 0) carry = 0;
    __syncthreads();
    for (int base = 0; base < C; base += SCAN_B) {
        int carryv = carry;
        int i = base + threadIdx.x;
        int v = (i < C) ? partials[i] : 0;
        s[threadIdx.x] = v;
        __syncthreads();
        #pragma unroll
        for (int off = 1; off < SCAN_B; off <<= 1) {
            int t = (threadIdx.x >= off) ? s[threadIdx.x - off] : 0;
            __syncthreads();
            s[threadIdx.x] += t;
            __syncthreads();
        }
        int total = s[SCAN_B - 1];
        if (i < C) partials[i] = s[threadIdx.x] - v + carryv;  // exclusive
        __syncthreads();
        if (threadIdx.x == 0) carry = carryv + total;
        __syncthreads();
    }
}

__global__ __launch_bounds__(SCAN_B) void finalize_rowptr(
    const int* __restrict__ counts, const int* __restrict__ tmp,
    const int* __restrict__ partials, int* __restrict__ rowptr,
    int* __restrict__ cursor, int n) {
    int i = blockIdx.x * SCAN_B + threadIdx.x;
    if (i >= n) return;
    int incl = partials[blockIdx.x] + tmp[i];
    rowptr[i + 1] = incl;
    cursor[i] = incl - counts[i];
    if (i == 0) rowptr[0] = 0;
}

// Packed scatter: one 8B store per edge (col,val) instead of two 4B stores.
__global__ __launch_bounds__(256) void scatter_edges(
    const int* __restrict__ rows, const int* __restrict__ cols,
    const float* __restrict__ vals, int* __restrict__ cursor,
    int2* __restrict__ spack, int nnz) {
    int e = blockIdx.x * blockDim.x + threadIdx.x;
    if (e >= nnz) return;
    int r = rows[e];
    int pos = atomicAdd(&cursor[r], 1);
    spack[pos] = make_int2(cols[e], __float_as_int(vals[e]));
}

// ---------------------------------------------------------------------------
// Gather SpMM (CSR): one wave per row, lane = dim.
// MODE 0: out = s
// MODE 1: out = s; acc = x[row] + s            (ui layer 1: acc = ego0 + ego1)
// MODE 2: out = s; acc += s                    (ui layer 2)
// MODE 3: acc += s                             (ui layer 3, no store)
// MODE 4: out = s; acc = acc*0.25 + s/max(||s||,eps)   (ii/uu final + epilogue)
// ---------------------------------------------------------------------------
template <int MODE>
__global__ __launch_bounds__(256) void spmm_csr(
    const int* __restrict__ rowptr, const int2* __restrict__ spack,
    const float* __restrict__ x, float* __restrict__ out,
    float* __restrict__ acc, int n_rows) {
    int w = (blockIdx.x * blockDim.x + threadIdx.x) >> 6;
    int lane = threadIdx.x & 63;
    if (w >= n_rows) return;
    int j = rowptr[w];
    int e = rowptr[w + 1];
    float s0 = 0.f, s1 = 0.f, s2 = 0.f, s3 = 0.f;
    for (; j + 3 < e; j += 4) {
        int2 p0 = spack[j], p1 = spack[j + 1], p2 = spack[j + 2], p3 = spack[j + 3];
        s0 += __int_as_float(p0.y) * x[(size_t)p0.x * DIM_C + lane];
        s1 += __int_as_float(p1.y) * x[(size_t)p1.x * DIM_C + lane];
        s2 += __int_as_float(p2.y) * x[(size_t)p2.x * DIM_C + lane];
        s3 += __int_as_float(p3.y) * x[(size_t)p3.x * DIM_C + lane];
    }
    for (; j < e; ++j) {
        int2 p = spack[j];
        s0 += __int_as_float(p.y) * x[(size_t)p.x * DIM_C + lane];
    }
    float s = (s0 + s1) + (s2 + s3);
    size_t idx = (size_t)w * DIM_C + lane;
    if (MODE == 0) {
        out[idx] = s;
    } else if (MODE == 1) {
        out[idx] = s;
        acc[idx] = x[idx] + s;
    } else if (MODE == 2) {
        out[idx] = s;
        acc[idx] += s;
    } else if (MODE == 3) {
        acc[idx] += s;
    } else if (MODE == 4) {
        out[idx] = s;
        float ss = s * s;
        #pragma unroll
        for (int off = 32; off > 0; off >>= 1) ss += __shfl_xor(ss, off, 64);
        float denom = fmaxf(sqrtf(ss), 1e-12f);
        acc[idx] = acc[idx] * 0.25f + s / denom;
    }
}

// ego0 concat: bufA = [user_ui; item_ui], float4-vectorized.
__global__ __launch_bounds__(256) void concat_init(
    const float* __restrict__ user_ui, const float* __restrict__ item_ui,
    float* __restrict__ dst) {
    int gid = blockIdx.x * blockDim.x + threadIdx.x;  // float4 index
    const int n4u = N_USERS_C * DIM_C / 4;
    const int n4  = NTOT_C * DIM_C / 4;
    if (gid >= n4) return;
    float4 v = (gid < n4u) ? ((const float4*)user_ui)[gid]
                           : ((const float4*)item_ui)[gid - n4u];
    ((float4*)dst)[gid] = v;
}

// ---------------------------------------------------------------------------

struct CsrWs {
    int2* spack;    // [max_nnz]
    int* counts;    // [NTOT]
    int* tmp;       // [NTOT]
    int* rowptr;    // [NTOT+1]
    int* cursor;    // [NTOT]
    int* partials;  // [1024]
};

static inline void build_csr(const int* rows, const int* cols, const float* vals,
                             int nnz, int n_rows, const CsrWs& W, hipStream_t s) {
    hipMemsetAsync(W.counts, 0, (size_t)n_rows * sizeof(int), s);
    int eb = (nnz + 255) / 256;
    hist_rows<<<eb, 256, 0, s>>>(rows, W.counts, nnz);
    int C = (n_rows + SCAN_B - 1) / SCAN_B;
    scan_chunks<<<C, SCAN_B, 0, s>>>(W.counts, W.tmp, W.partials, n_rows);
    scan_partials<<<1, SCAN_B, 0, s>>>(W.partials, C);
    finalize_rowptr<<<C, SCAN_B, 0, s>>>(W.counts, W.tmp, W.partials,
                                         W.rowptr, W.cursor, n_rows);
    scatter_edges<<<eb, 256, 0, s>>>(rows, cols, vals, W.cursor, W.spack, nnz);
}

template <int MODE>
static inline void run_spmm(const CsrWs& W, const float* x, float* out, float* acc,
                            int n_rows, hipStream_t s) {
    int blocks = (n_rows * 64 + 255) / 256;
    spmm_csr<MODE><<<blocks, 256, 0, s>>>(W.rowptr, W.spack, x, out, acc, n_rows);
}

extern "C" void kernel_launch(void* const* d_in, const int* in_sizes, int n_in,
                              void* d_out, int out_size, void* d_ws, size_t ws_size,
                              hipStream_t stream) {
    const float* user_ui = (const float*)d_in[0];
    const float* item_ui = (const float*)d_in[1];
    const float* uu_emb  = (const float*)d_in[2];
    const float* ii_emb  = (const float*)d_in[3];
    const float* ui_vals = (const float*)d_in[4];
    const float* ii_vals = (const float*)d_in[5];
    const float* uu_vals = (const float*)d_in[6];
    const int* ui_rows = (const int*)d_in[7];
    const int* ui_cols = (const int*)d_in[8];
    const int* ii_rows = (const int*)d_in[9];
    const int* ii_cols = (const int*)d_in[10];
    const int* uu_rows = (const int*)d_in[11];
    const int* uu_cols = (const int*)d_in[12];
    const int nnz_ui = in_sizes[4];
    const int nnz_ii = in_sizes[5];
    const int nnz_uu = in_sizes[6];
    const int max_nnz = nnz_ui > nnz_uu ? (nnz_ui > nnz_ii ? nnz_ui : nnz_ii)
                                        : (nnz_uu > nnz_ii ? nnz_uu : nnz_ii);

    float* out    = (float*)d_out;
    float* acc    = out;                                  // [140000, 64]
    float* acc_u  = acc;                                  // users part
    float* acc_i  = acc + (size_t)N_USERS_C * DIM_C;      // items part
    float* out_ii = out + (size_t)NTOT_C * DIM_C;         // [40000, 64]
    float* out_uu = out_ii + (size_t)N_ITEMS_C * DIM_C;   // [100000, 64]
    float* out_tail = out_ii;  // NTOT*64 contiguous scratch (before final layers)

    // Workspace carve-up
    char* p = (char*)d_ws;
    float* bufA = (float*)p;               p += (size_t)NTOT_C * DIM_C * sizeof(float);
    CsrWs W;
    W.spack    = (int2*)p;                 p += (size_t)max_nnz * sizeof(int2);
    W.counts   = (int*)p;                  p += (size_t)NTOT_C * sizeof(int);
    W.tmp      = (int*)p;                  p += (size_t)NTOT_C * sizeof(int);
    W.rowptr   = (int*)p;                  p += (size_t)(NTOT_C + 1) * sizeof(int);
    W.cursor   = (int*)p;                  p += (size_t)NTOT_C * sizeof(int);
    W.partials = (int*)p;                  p += 1024 * sizeof(int);

    // ==== ui chain (3 layers; acc lives in d_out head) ====
    build_csr(ui_rows, ui_cols, ui_vals, nnz_ui, NTOT_C, W, stream);
    {
        int n4 = NTOT_C * DIM_C / 4;
        concat_init<<<(n4 + 255) / 256, 256, 0, stream>>>(user_ui, item_ui, bufA);
    }
    // L1: ego1 = S*ego0(bufA) -> out_tail; acc = ego0 + ego1 (x[idx] + s)
    run_spmm<1>(W, bufA, out_tail, acc, NTOT_C, stream);
    // L2: ego2 = S*ego1(out_tail) -> bufA; acc += ego2
    run_spmm<2>(W, out_tail, bufA, acc, NTOT_C, stream);
    // L3: ego3 = S*ego2(bufA); acc += ego3 (no store)
    run_spmm<3>(W, bufA, nullptr, acc, NTOT_C, stream);

    // ==== ii chain (2 layers; final fuses acc epilogue for item rows) ====
    build_csr(ii_rows, ii_cols, ii_vals, nnz_ii, N_ITEMS_C, W, stream);
    run_spmm<0>(W, ii_emb, bufA, nullptr, N_ITEMS_C, stream);
    run_spmm<4>(W, bufA, out_ii, acc_i, N_ITEMS_C, stream);

    // ==== uu chain (2 layers; final fuses acc epilogue for user rows) ====
    build_csr(uu_rows, uu_cols, uu_vals, nnz_uu, N_USERS_C, W, stream);
    run_spmm<0>(W, uu_emb, bufA, nullptr, N_USERS_C, stream);
    run_spmm<4>(W, bufA, out_uu, acc_u, N_USERS_C, stream);
}

// Round 4
// 1084.204 us; speedup vs baseline: 1.0214x; 1.0214x over previous
//
#include <hip/hip_runtime.h>

#define N_USERS_C 100000
#define N_ITEMS_C 40000
#define NTOT_C    140000
#define DIM_C     64
#define SCAN_B    256

// f32 -> bf16 round-to-nearest-even
__device__ __forceinline__ unsigned short f2bf(float f) {
    unsigned u = __float_as_uint(f);
    unsigned r = (u + 0x7FFFu + ((u >> 16) & 1u)) >> 16;
    return (unsigned short)r;
}
__device__ __forceinline__ float bf2f(unsigned short h) {
    return __uint_as_float((unsigned)h << 16);
}

// ---------------------------------------------------------------------------
// CSR build: histogram -> chunked inclusive scan -> partials scan -> finalize
// ---------------------------------------------------------------------------
__global__ __launch_bounds__(256) void hist_rows(
    const int* __restrict__ rows, int* __restrict__ counts, int nnz) {
    int e = blockIdx.x * blockDim.x + threadIdx.x;
    if (e < nnz) atomicAdd(&counts[rows[e]], 1);
}

__global__ __launch_bounds__(SCAN_B) void scan_chunks(
    const int* __restrict__ counts, int* __restrict__ tmp,
    int* __restrict__ partials, int n) {
    __shared__ int s[SCAN_B];
    int i = blockIdx.x * SCAN_B + threadIdx.x;
    int v = (i < n) ? counts[i] : 0;
    s[threadIdx.x] = v;
    __syncthreads();
    #pragma unroll
    for (int off = 1; off < SCAN_B; off <<= 1) {
        int t = (threadIdx.x >= off) ? s[threadIdx.x - off] : 0;
        __syncthreads();
        s[threadIdx.x] += t;
        __syncthreads();
    }
    if (i < n) tmp[i] = s[threadIdx.x];
    if (threadIdx.x == SCAN_B - 1) partials[blockIdx.x] = s[SCAN_B - 1];
}

__global__ __launch_bounds__(SCAN_B) void scan_partials(int* __restrict__ partials, int C) {
    __shared__ int s[SCAN_B];
    __shared__ int carry;
    if (threadIdx.x == 0) carry = 0;
    __syncthreads();
    for (int base = 0; base < C; base += SCAN_B) {
        int carryv = carry;
        int i = base + threadIdx.x;
        int v = (i < C) ? partials[i] : 0;
        s[threadIdx.x] = v;
        __syncthreads();
        #pragma unroll
        for (int off = 1; off < SCAN_B; off <<= 1) {
            int t = (threadIdx.x >= off) ? s[threadIdx.x - off] : 0;
            __syncthreads();
            s[threadIdx.x] += t;
            __syncthreads();
        }
        int total = s[SCAN_B - 1];
        if (i < C) partials[i] = s[threadIdx.x] - v + carryv;  // exclusive
        __syncthreads();
        if (threadIdx.x == 0) carry = carryv + total;
        __syncthreads();
    }
}

__global__ __launch_bounds__(SCAN_B) void finalize_rowptr(
    const int* __restrict__ counts, const int* __restrict__ tmp,
    const int* __restrict__ partials, int* __restrict__ rowptr,
    int* __restrict__ cursor, int n) {
    int i = blockIdx.x * SCAN_B + threadIdx.x;
    if (i >= n) return;
    int incl = partials[blockIdx.x] + tmp[i];
    rowptr[i + 1] = incl;
    cursor[i] = incl - counts[i];
    if (i == 0) rowptr[0] = 0;
}

__global__ __launch_bounds__(256) void scatter_edges(
    const int* __restrict__ rows, const int* __restrict__ cols,
    const float* __restrict__ vals, int* __restrict__ cursor,
    int2* __restrict__ spack, int nnz) {
    int e = blockIdx.x * blockDim.x + threadIdx.x;
    if (e >= nnz) return;
    int r = rows[e];
    int pos = atomicAdd(&cursor[r], 1);
    spack[pos] = make_int2(cols[e], __float_as_int(vals[e]));
}

// f32 -> bf16 conversion, 4 elems/thread (float4 load, ushort4 store)
__global__ __launch_bounds__(256) void to_bf16(
    const float* __restrict__ src, unsigned short* __restrict__ dst, int n4) {
    int gid = blockIdx.x * blockDim.x + threadIdx.x;
    if (gid >= n4) return;
    float4 v = ((const float4*)src)[gid];
    ushort4 o;
    o.x = f2bf(v.x); o.y = f2bf(v.y); o.z = f2bf(v.z); o.w = f2bf(v.w);
    ((ushort4*)dst)[gid] = o;
}

// Dual-source variant for ego0 = [user_ui; item_ui]
__global__ __launch_bounds__(256) void concat_to_bf16(
    const float* __restrict__ user_ui, const float* __restrict__ item_ui,
    unsigned short* __restrict__ dst) {
    int gid = blockIdx.x * blockDim.x + threadIdx.x;  // float4 index
    const int n4u = N_USERS_C * DIM_C / 4;
    const int n4  = NTOT_C * DIM_C / 4;
    if (gid >= n4) return;
    float4 v = (gid < n4u) ? ((const float4*)user_ui)[gid]
                           : ((const float4*)item_ui)[gid - n4u];
    ushort4 o;
    o.x = f2bf(v.x); o.y = f2bf(v.y); o.z = f2bf(v.z); o.w = f2bf(v.w);
    ((ushort4*)dst)[gid] = o;
}

// ---------------------------------------------------------------------------
// Gather SpMM (CSR), bf16 feature gather, f32 accumulate. Wave per row,
// lane = dim.
// MODE 0: out_bf = bf16(s)
// MODE 1: out_bf = bf16(s); acc = ego0_f32[row] + s     (ui layer 1)
// MODE 2: out_bf = bf16(s); acc += s                    (ui layer 2)
// MODE 3: acc += s                                      (ui layer 3)
// MODE 4: out_f32 = s; acc = acc*0.25 + s/max(||s||,eps) (ii/uu final)
// ---------------------------------------------------------------------------
template <int MODE>
__global__ __launch_bounds__(256) void spmm_csr(
    const int* __restrict__ rowptr, const int2* __restrict__ spack,
    const unsigned short* __restrict__ x, unsigned short* __restrict__ out_bf,
    float* __restrict__ out_f32, float* __restrict__ acc,
    const float* __restrict__ ego_u, const float* __restrict__ ego_i,
    int n_rows) {
    int w = (blockIdx.x * blockDim.x + threadIdx.x) >> 6;
    int lane = threadIdx.x & 63;
    if (w >= n_rows) return;
    int j = rowptr[w];
    int e = rowptr[w + 1];
    float s0 = 0.f, s1 = 0.f, s2 = 0.f, s3 = 0.f;
    for (; j + 3 < e; j += 4) {
        int2 p0 = spack[j], p1 = spack[j + 1], p2 = spack[j + 2], p3 = spack[j + 3];
        s0 += __int_as_float(p0.y) * bf2f(x[(size_t)p0.x * DIM_C + lane]);
        s1 += __int_as_float(p1.y) * bf2f(x[(size_t)p1.x * DIM_C + lane]);
        s2 += __int_as_float(p2.y) * bf2f(x[(size_t)p2.x * DIM_C + lane]);
        s3 += __int_as_float(p3.y) * bf2f(x[(size_t)p3.x * DIM_C + lane]);
    }
    for (; j < e; ++j) {
        int2 p = spack[j];
        s0 += __int_as_float(p.y) * bf2f(x[(size_t)p.x * DIM_C + lane]);
    }
    float s = (s0 + s1) + (s2 + s3);
    size_t idx = (size_t)w * DIM_C + lane;
    if (MODE == 0) {
        out_bf[idx] = f2bf(s);
    } else if (MODE == 1) {
        out_bf[idx] = f2bf(s);
        float ego0 = (w < N_USERS_C)
            ? ego_u[idx]
            : ego_i[(size_t)(w - N_USERS_C) * DIM_C + lane];
        acc[idx] = ego0 + s;
    } else if (MODE == 2) {
        out_bf[idx] = f2bf(s);
        acc[idx] += s;
    } else if (MODE == 3) {
        acc[idx] += s;
    } else if (MODE == 4) {
        out_f32[idx] = s;
        float ss = s * s;
        #pragma unroll
        for (int off = 32; off > 0; off >>= 1) ss += __shfl_xor(ss, off, 64);
        float denom = fmaxf(sqrtf(ss), 1e-12f);
        acc[idx] = acc[idx] * 0.25f + s / denom;
    }
}

// ---------------------------------------------------------------------------

struct CsrWs {
    int2* spack;    // [max_nnz]
    int* counts;    // [NTOT]
    int* tmp;       // [NTOT]
    int* rowptr;    // [NTOT+1]
    int* cursor;    // [NTOT]
    int* partials;  // [1024]
};

static inline void build_csr(const int* rows, const int* cols, const float* vals,
                             int nnz, int n_rows, const CsrWs& W, hipStream_t s) {
    hipMemsetAsync(W.counts, 0, (size_t)n_rows * sizeof(int), s);
    int eb = (nnz + 255) / 256;
    hist_rows<<<eb, 256, 0, s>>>(rows, W.counts, nnz);
    int C = (n_rows + SCAN_B - 1) / SCAN_B;
    scan_chunks<<<C, SCAN_B, 0, s>>>(W.counts, W.tmp, W.partials, n_rows);
    scan_partials<<<1, SCAN_B, 0, s>>>(W.partials, C);
    finalize_rowptr<<<C, SCAN_B, 0, s>>>(W.counts, W.tmp, W.partials,
                                         W.rowptr, W.cursor, n_rows);
    scatter_edges<<<eb, 256, 0, s>>>(rows, cols, vals, W.cursor, W.spack, nnz);
}

template <int MODE>
static inline void run_spmm(const CsrWs& W, const unsigned short* x,
                            unsigned short* out_bf, float* out_f32, float* acc,
                            const float* ego_u, const float* ego_i,
                            int n_rows, hipStream_t s) {
    int blocks = (n_rows * 64 + 255) / 256;
    spmm_csr<MODE><<<blocks, 256, 0, s>>>(W.rowptr, W.spack, x, out_bf, out_f32,
                                          acc, ego_u, ego_i, n_rows);
}

extern "C" void kernel_launch(void* const* d_in, const int* in_sizes, int n_in,
                              void* d_out, int out_size, void* d_ws, size_t ws_size,
                              hipStream_t stream) {
    const float* user_ui = (const float*)d_in[0];
    const float* item_ui = (const float*)d_in[1];
    const float* uu_emb  = (const float*)d_in[2];
    const float* ii_emb  = (const float*)d_in[3];
    const float* ui_vals = (const float*)d_in[4];
    const float* ii_vals = (const float*)d_in[5];
    const float* uu_vals = (const float*)d_in[6];
    const int* ui_rows = (const int*)d_in[7];
    const int* ui_cols = (const int*)d_in[8];
    const int* ii_rows = (const int*)d_in[9];
    const int* ii_cols = (const int*)d_in[10];
    const int* uu_rows = (const int*)d_in[11];
    const int* uu_cols = (const int*)d_in[12];
    const int nnz_ui = in_sizes[4];
    const int nnz_ii = in_sizes[5];
    const int nnz_uu = in_sizes[6];
    const int max_nnz = nnz_ui > nnz_uu ? (nnz_ui > nnz_ii ? nnz_ui : nnz_ii)
                                        : (nnz_uu > nnz_ii ? nnz_uu : nnz_ii);

    float* out    = (float*)d_out;
    float* acc    = out;                                  // [140000, 64]
    float* acc_u  = acc;
    float* acc_i  = acc + (size_t)N_USERS_C * DIM_C;
    float* out_ii = out + (size_t)NTOT_C * DIM_C;         // [40000, 64]
    float* out_uu = out_ii + (size_t)N_ITEMS_C * DIM_C;   // [100000, 64]

    // Workspace carve-up
    char* p = (char*)d_ws;
    unsigned short* buf0 = (unsigned short*)p;  p += (size_t)NTOT_C * DIM_C * sizeof(unsigned short);
    unsigned short* buf1 = (unsigned short*)p;  p += (size_t)NTOT_C * DIM_C * sizeof(unsigned short);
    CsrWs W;
    W.spack    = (int2*)p;                 p += (size_t)max_nnz * sizeof(int2);
    W.counts   = (int*)p;                  p += (size_t)NTOT_C * sizeof(int);
    W.tmp      = (int*)p;                  p += (size_t)NTOT_C * sizeof(int);
    W.rowptr   = (int*)p;                  p += (size_t)(NTOT_C + 1) * sizeof(int);
    W.cursor   = (int*)p;                  p += (size_t)NTOT_C * sizeof(int);
    W.partials = (int*)p;                  p += 1024 * sizeof(int);

    // ==== ui chain (3 layers; acc lives in d_out head) ====
    build_csr(ui_rows, ui_cols, ui_vals, nnz_ui, NTOT_C, W, stream);
    {
        int n4 = NTOT_C * DIM_C / 4;
        concat_to_bf16<<<(n4 + 255) / 256, 256, 0, stream>>>(user_ui, item_ui, buf1);
    }
    // L1: s = S*ego0(buf1); buf0 = bf16(s); acc = ego0_f32 + s
    run_spmm<1>(W, buf1, buf0, nullptr, acc, user_ui, item_ui, NTOT_C, stream);
    // L2: s = S*ego1(buf0); buf1 = bf16(s); acc += s
    run_spmm<2>(W, buf0, buf1, nullptr, acc, nullptr, nullptr, NTOT_C, stream);
    // L3: s = S*ego2(buf1); acc += s
    run_spmm<3>(W, buf1, nullptr, nullptr, acc, nullptr, nullptr, NTOT_C, stream);

    // ==== ii chain (2 layers; final fuses epilogue for item rows) ====
    build_csr(ii_rows, ii_cols, ii_vals, nnz_ii, N_ITEMS_C, W, stream);
    {
        int n4 = N_ITEMS_C * DIM_C / 4;
        to_bf16<<<(n4 + 255) / 256, 256, 0, stream>>>(ii_emb, buf0, n4);
    }
    run_spmm<0>(W, buf0, buf1, nullptr, nullptr, nullptr, nullptr, N_ITEMS_C, stream);
    run_spmm<4>(W, buf1, nullptr, out_ii, acc_i, nullptr, nullptr, N_ITEMS_C, stream);

    // ==== uu chain (2 layers; final fuses epilogue for user rows) ====
    build_csr(uu_rows, uu_cols, uu_vals, nnz_uu, N_USERS_C, W, stream);
    {
        int n4 = N_USERS_C * DIM_C / 4;
        to_bf16<<<(n4 + 255) / 256, 256, 0, stream>>>(uu_emb, buf0, n4);
    }
    run_spmm<0>(W, buf0, buf1, nullptr, nullptr, nullptr, nullptr, N_USERS_C, stream);
    run_spmm<4>(W, buf1, nullptr, out_uu, acc_u, nullptr, nullptr, N_USERS_C, stream);
}

// Round 5
// 860.497 us; speedup vs baseline: 1.2869x; 1.2600x over previous
//
#include <hip/hip_runtime.h>

#define N_USERS_C 100000
#define N_ITEMS_C 40000
#define NTOT_C    140000
#define DIM_C     64

// f32 -> bf16 round-to-nearest-even
__device__ __forceinline__ unsigned short f2bf(float f) {
    unsigned u = __float_as_uint(f);
    unsigned r = (u + 0x7FFFu + ((u >> 16) & 1u)) >> 16;
    return (unsigned short)r;
}
__device__ __forceinline__ float bf2f(unsigned short h) {
    return __uint_as_float((unsigned)h << 16);
}

// ---------------------------------------------------------------------------
// Bucketed counting-sort CSR build.
// Bucket = contiguous range of BR rows (BR = 1<<LOG_BR), NB = ceil(n/BR) <= 256.
// inter[] entry: x = (row_local << 18) | col  (col < 2^18), y = val bits.
// ---------------------------------------------------------------------------

// P0: LDS-aggregated bucket histogram. bkt_count must be pre-zeroed.
template <int LOG_BR>
__global__ __launch_bounds__(256) void bucket_hist(
    const int* __restrict__ rows, int* __restrict__ bkt_count, int nnz, int NB) {
    __shared__ int cnt[256];
    if (threadIdx.x < NB) cnt[threadIdx.x] = 0;
    __syncthreads();
    for (int e = blockIdx.x * 256 + threadIdx.x; e < nnz; e += gridDim.x * 256)
        atomicAdd(&cnt[rows[e] >> LOG_BR], 1);
    __syncthreads();
    if (threadIdx.x < NB) {
        int c = cnt[threadIdx.x];
        if (c) atomicAdd(&bkt_count[threadIdx.x], c);
    }
}

// S0: single-block exclusive scan of NB bucket counts -> bkt_start (+sentinel),
// and init bkt_cursor.
__global__ __launch_bounds__(256) void bucket_scan(
    const int* __restrict__ bkt_count, int* __restrict__ bkt_start,
    int* __restrict__ bkt_cursor, int NB, int nnz) {
    __shared__ int s[256];
    int v = (threadIdx.x < NB) ? bkt_count[threadIdx.x] : 0;
    s[threadIdx.x] = v;
    __syncthreads();
    #pragma unroll
    for (int off = 1; off < 256; off <<= 1) {
        int t = (threadIdx.x >= off) ? s[threadIdx.x - off] : 0;
        __syncthreads();
        s[threadIdx.x] += t;
        __syncthreads();
    }
    if (threadIdx.x < NB) {
        int ex = s[threadIdx.x] - v;
        bkt_start[threadIdx.x] = ex;
        bkt_cursor[threadIdx.x] = ex;
    }
    if (threadIdx.x == 0) bkt_start[NB] = nnz;
}

// P1: block-aggregated partition into bucket-major intermediate array.
// One 4096-edge tile per block; per-bucket chunks written contiguously.
template <int LOG_BR>
__global__ __launch_bounds__(256) void partition_edges(
    const int* __restrict__ rows, const int* __restrict__ cols,
    const float* __restrict__ vals, int* __restrict__ bkt_cursor,
    int2* __restrict__ inter, int nnz) {
    __shared__ int cnt[256];
    __shared__ int base[256];
    const int tile = blockIdx.x * 4096;
    cnt[threadIdx.x] = 0;
    __syncthreads();
    int myrow[16];
    #pragma unroll
    for (int i = 0; i < 16; ++i) {
        int e = tile + i * 256 + threadIdx.x;
        int r = (e < nnz) ? rows[e] : -1;
        myrow[i] = r;
        if (r >= 0) atomicAdd(&cnt[r >> LOG_BR], 1);
    }
    __syncthreads();
    {
        int c = cnt[threadIdx.x];
        if (c) base[threadIdx.x] = atomicAdd(&bkt_cursor[threadIdx.x], c);
        cnt[threadIdx.x] = 0;  // reuse as rank counter
    }
    __syncthreads();
    #pragma unroll
    for (int i = 0; i < 16; ++i) {
        int r = myrow[i];
        if (r < 0) continue;
        int b = r >> LOG_BR;
        int rank = atomicAdd(&cnt[b], 1);
        int e = tile + i * 256 + threadIdx.x;
        int rl = r & ((1 << LOG_BR) - 1);
        inter[base[b] + rank] = make_int2((rl << 18) | cols[e],
                                          __float_as_int(vals[e]));
    }
}

// P2: one block per bucket. LDS row-hist + block scan -> rowptr + LDS cursors,
// then scatter (col,val) to final CSR positions (L2-window-local writes).
template <int LOG_BR>
__global__ __launch_bounds__(256) void bucket_to_csr(
    const int* __restrict__ bkt_start, const int2* __restrict__ inter,
    int2* __restrict__ spack, int* __restrict__ rowptr, int n_rows, int nnz) {
    const int BR = 1 << LOG_BR;
    const int C = BR / 256;  // rows per thread: 1, 2, or 4
    __shared__ int hist[BR];
    __shared__ int bsum[256];
    const int b = blockIdx.x;
    const int lo = bkt_start[b], hi = bkt_start[b + 1];
    #pragma unroll
    for (int j = 0; j < C; ++j) hist[threadIdx.x * C + j] = 0;
    __syncthreads();
    for (int i = lo + threadIdx.x; i < hi; i += 256)
        atomicAdd(&hist[inter[i].x >> 18], 1);
    __syncthreads();
    // thread-local prefix over C contiguous rows, then block scan of sums
    int loc[4];
    int sum = 0;
    #pragma unroll
    for (int j = 0; j < C; ++j) { loc[j] = sum; sum += hist[threadIdx.x * C + j]; }
    bsum[threadIdx.x] = sum;
    __syncthreads();
    #pragma unroll
    for (int off = 1; off < 256; off <<= 1) {
        int t = (threadIdx.x >= off) ? bsum[threadIdx.x - off] : 0;
        __syncthreads();
        bsum[threadIdx.x] += t;
        __syncthreads();
    }
    int texcl = bsum[threadIdx.x] - sum;
    __syncthreads();
    #pragma unroll
    for (int j = 0; j < C; ++j) {
        int r = threadIdx.x * C + j;
        int abs0 = lo + texcl + loc[j];
        int grow = (b << LOG_BR) + r;
        if (grow < n_rows) rowptr[grow] = abs0;
        hist[r] = abs0;  // absolute cursor
    }
    if (b == gridDim.x - 1 && threadIdx.x == 0) rowptr[n_rows] = nnz;
    __syncthreads();
    for (int i = lo + threadIdx.x; i < hi; i += 256) {
        int2 p = inter[i];
        int pos = atomicAdd(&hist[p.x >> 18], 1);
        spack[pos] = make_int2(p.x & 0x3FFFF, p.y);
    }
}

// ---------------------------------------------------------------------------
// f32 -> bf16 conversion kernels
// ---------------------------------------------------------------------------
__global__ __launch_bounds__(256) void to_bf16(
    const float* __restrict__ src, unsigned short* __restrict__ dst, int n4) {
    int gid = blockIdx.x * blockDim.x + threadIdx.x;
    if (gid >= n4) return;
    float4 v = ((const float4*)src)[gid];
    ushort4 o;
    o.x = f2bf(v.x); o.y = f2bf(v.y); o.z = f2bf(v.z); o.w = f2bf(v.w);
    ((ushort4*)dst)[gid] = o;
}

__global__ __launch_bounds__(256) void concat_to_bf16(
    const float* __restrict__ user_ui, const float* __restrict__ item_ui,
    unsigned short* __restrict__ dst) {
    int gid = blockIdx.x * blockDim.x + threadIdx.x;
    const int n4u = N_USERS_C * DIM_C / 4;
    const int n4  = NTOT_C * DIM_C / 4;
    if (gid >= n4) return;
    float4 v = (gid < n4u) ? ((const float4*)user_ui)[gid]
                           : ((const float4*)item_ui)[gid - n4u];
    ushort4 o;
    o.x = f2bf(v.x); o.y = f2bf(v.y); o.z = f2bf(v.z); o.w = f2bf(v.w);
    ((ushort4*)dst)[gid] = o;
}

// ---------------------------------------------------------------------------
// Gather SpMM (CSR), bf16 feature gather, f32 accumulate. Wave per row.
// MODE 0: out_bf = bf16(s)
// MODE 1: out_bf = bf16(s); acc = ego0_f32[row] + s     (ui layer 1)
// MODE 2: out_bf = bf16(s); acc += s                    (ui layer 2)
// MODE 3: acc += s                                      (ui layer 3)
// MODE 4: out_f32 = s; acc = acc*0.25 + s/max(||s||,eps) (ii/uu final)
// ---------------------------------------------------------------------------
template <int MODE>
__global__ __launch_bounds__(256) void spmm_csr(
    const int* __restrict__ rowptr, const int2* __restrict__ spack,
    const unsigned short* __restrict__ x, unsigned short* __restrict__ out_bf,
    float* __restrict__ out_f32, float* __restrict__ acc,
    const float* __restrict__ ego_u, const float* __restrict__ ego_i,
    int n_rows) {
    int w = (blockIdx.x * blockDim.x + threadIdx.x) >> 6;
    int lane = threadIdx.x & 63;
    if (w >= n_rows) return;
    int j = rowptr[w];
    int e = rowptr[w + 1];
    float s0 = 0.f, s1 = 0.f, s2 = 0.f, s3 = 0.f;
    for (; j + 3 < e; j += 4) {
        int2 p0 = spack[j], p1 = spack[j + 1], p2 = spack[j + 2], p3 = spack[j + 3];
        s0 += __int_as_float(p0.y) * bf2f(x[(size_t)p0.x * DIM_C + lane]);
        s1 += __int_as_float(p1.y) * bf2f(x[(size_t)p1.x * DIM_C + lane]);
        s2 += __int_as_float(p2.y) * bf2f(x[(size_t)p2.x * DIM_C + lane]);
        s3 += __int_as_float(p3.y) * bf2f(x[(size_t)p3.x * DIM_C + lane]);
    }
    for (; j < e; ++j) {
        int2 p = spack[j];
        s0 += __int_as_float(p.y) * bf2f(x[(size_t)p.x * DIM_C + lane]);
    }
    float s = (s0 + s1) + (s2 + s3);
    size_t idx = (size_t)w * DIM_C + lane;
    if (MODE == 0) {
        out_bf[idx] = f2bf(s);
    } else if (MODE == 1) {
        out_bf[idx] = f2bf(s);
        float ego0 = (w < N_USERS_C)
            ? ego_u[idx]
            : ego_i[(size_t)(w - N_USERS_C) * DIM_C + lane];
        acc[idx] = ego0 + s;
    } else if (MODE == 2) {
        out_bf[idx] = f2bf(s);
        acc[idx] += s;
    } else if (MODE == 3) {
        acc[idx] += s;
    } else if (MODE == 4) {
        out_f32[idx] = s;
        float ss = s * s;
        #pragma unroll
        for (int off = 32; off > 0; off >>= 1) ss += __shfl_xor(ss, off, 64);
        float denom = fmaxf(sqrtf(ss), 1e-12f);
        acc[idx] = acc[idx] * 0.25f + s / denom;
    }
}

// ---------------------------------------------------------------------------

struct BuildWs {
    int2* spack;      // [max_nnz] final CSR (col,val)
    int2* inter;      // [max_nnz] bucket-major intermediate (aliases buf0)
    int* rowptr;      // [NTOT+1]
    int* bkt_count;   // [257]
    int* bkt_start;   // [258]
    int* bkt_cursor;  // [257]
};

template <int LOG_BR>
static inline void build_csr(const int* rows, const int* cols, const float* vals,
                             int nnz, int n_rows, const BuildWs& W, hipStream_t s) {
    const int NB = (n_rows + (1 << LOG_BR) - 1) >> LOG_BR;
    hipMemsetAsync(W.bkt_count, 0, (size_t)NB * sizeof(int), s);
    bucket_hist<LOG_BR><<<512, 256, 0, s>>>(rows, W.bkt_count, nnz, NB);
    bucket_scan<<<1, 256, 0, s>>>(W.bkt_count, W.bkt_start, W.bkt_cursor, NB, nnz);
    int p1b = (nnz + 4095) / 4096;
    partition_edges<LOG_BR><<<p1b, 256, 0, s>>>(rows, cols, vals, W.bkt_cursor,
                                                W.inter, nnz);
    bucket_to_csr<LOG_BR><<<NB, 256, 0, s>>>(W.bkt_start, W.inter, W.spack,
                                             W.rowptr, n_rows, nnz);
}

template <int MODE>
static inline void run_spmm(const int* rowptr, const int2* spack,
                            const unsigned short* x, unsigned short* out_bf,
                            float* out_f32, float* acc, const float* ego_u,
                            const float* ego_i, int n_rows, hipStream_t s) {
    int blocks = (n_rows * 64 + 255) / 256;
    spmm_csr<MODE><<<blocks, 256, 0, s>>>(rowptr, spack, x, out_bf, out_f32,
                                          acc, ego_u, ego_i, n_rows);
}

extern "C" void kernel_launch(void* const* d_in, const int* in_sizes, int n_in,
                              void* d_out, int out_size, void* d_ws, size_t ws_size,
                              hipStream_t stream) {
    const float* user_ui = (const float*)d_in[0];
    const float* item_ui = (const float*)d_in[1];
    const float* uu_emb  = (const float*)d_in[2];
    const float* ii_emb  = (const float*)d_in[3];
    const float* ui_vals = (const float*)d_in[4];
    const float* ii_vals = (const float*)d_in[5];
    const float* uu_vals = (const float*)d_in[6];
    const int* ui_rows = (const int*)d_in[7];
    const int* ui_cols = (const int*)d_in[8];
    const int* ii_rows = (const int*)d_in[9];
    const int* ii_cols = (const int*)d_in[10];
    const int* uu_rows = (const int*)d_in[11];
    const int* uu_cols = (const int*)d_in[12];
    const int nnz_ui = in_sizes[4];
    const int nnz_ii = in_sizes[5];
    const int nnz_uu = in_sizes[6];
    const int max_nnz = nnz_ui > nnz_uu ? (nnz_ui > nnz_ii ? nnz_ui : nnz_ii)
                                        : (nnz_uu > nnz_ii ? nnz_uu : nnz_ii);

    float* out    = (float*)d_out;
    float* acc    = out;                                  // [140000, 64]
    float* acc_u  = acc;
    float* acc_i  = acc + (size_t)N_USERS_C * DIM_C;
    float* out_ii = out + (size_t)NTOT_C * DIM_C;         // [40000, 64]
    float* out_uu = out_ii + (size_t)N_ITEMS_C * DIM_C;   // [100000, 64]

    // Workspace carve-up (inter aliases buf0: inter is dead before buf0 is written)
    char* p = (char*)d_ws;
    BuildWs W;
    W.spack = (int2*)p;                         p += (size_t)max_nnz * sizeof(int2);
    unsigned short* buf0 = (unsigned short*)p;
    W.inter = (int2*)p;                         p += (size_t)NTOT_C * DIM_C * sizeof(unsigned short);
    unsigned short* buf1 = (unsigned short*)p;  p += (size_t)NTOT_C * DIM_C * sizeof(unsigned short);
    W.rowptr     = (int*)p;                     p += (size_t)(NTOT_C + 1) * sizeof(int);
    W.bkt_count  = (int*)p;                     p += 257 * sizeof(int);
    W.bkt_start  = (int*)p;                     p += 258 * sizeof(int);
    W.bkt_cursor = (int*)p;                     p += 257 * sizeof(int);

    // ==== ui chain (3 layers; acc lives in d_out head); BR=1024, NB=137 ====
    build_csr<10>(ui_rows, ui_cols, ui_vals, nnz_ui, NTOT_C, W, stream);
    {
        int n4 = NTOT_C * DIM_C / 4;
        concat_to_bf16<<<(n4 + 255) / 256, 256, 0, stream>>>(user_ui, item_ui, buf1);
    }
    // L1: s = S*ego0(buf1); buf0 = bf16(s) (overwrites dead inter); acc = ego0 + s
    run_spmm<1>(W.rowptr, W.spack, buf1, buf0, nullptr, acc, user_ui, item_ui,
                NTOT_C, stream);
    // L2: s = S*ego1(buf0); buf1 = bf16(s); acc += s
    run_spmm<2>(W.rowptr, W.spack, buf0, buf1, nullptr, acc, nullptr, nullptr,
                NTOT_C, stream);
    // L3: s = S*ego2(buf1); acc += s
    run_spmm<3>(W.rowptr, W.spack, buf1, nullptr, nullptr, acc, nullptr, nullptr,
                NTOT_C, stream);

    // ==== ii chain (2 layers; final fuses epilogue); BR=256, NB=157 ====
    build_csr<8>(ii_rows, ii_cols, ii_vals, nnz_ii, N_ITEMS_C, W, stream);
    {
        int n4 = N_ITEMS_C * DIM_C / 4;
        to_bf16<<<(n4 + 255) / 256, 256, 0, stream>>>(ii_emb, buf0, n4);
    }
    run_spmm<0>(W.rowptr, W.spack, buf0, buf1, nullptr, nullptr, nullptr, nullptr,
                N_ITEMS_C, stream);
    run_spmm<4>(W.rowptr, W.spack, buf1, nullptr, out_ii, acc_i, nullptr, nullptr,
                N_ITEMS_C, stream);

    // ==== uu chain (2 layers; final fuses epilogue); BR=512, NB=196 ====
    build_csr<9>(uu_rows, uu_cols, uu_vals, nnz_uu, N_USERS_C, W, stream);
    {
        int n4 = N_USERS_C * DIM_C / 4;
        to_bf16<<<(n4 + 255) / 256, 256, 0, stream>>>(uu_emb, buf0, n4);
    }
    run_spmm<0>(W.rowptr, W.spack, buf0, buf1, nullptr, nullptr, nullptr, nullptr,
                N_USERS_C, stream);
    run_spmm<4>(W.rowptr, W.spack, buf1, nullptr, out_uu, acc_u, nullptr, nullptr,
                N_USERS_C, stream);
}